// Round 10
// baseline (103.991 us; speedup 1.0000x reference)
//
#include <hip/hip_runtime.h>
#include <hip/hip_bf16.h>
#include <math.h>

// CapsNet dynamic routing. R26 = R25 + single-pass online-softmax b-update.
// R25 post-mortem: caps ~42.5us; bench gap decoded = ws re-poison fill
// (~45us, harness, unavoidable) + 2 launches (~10) + convert (~4).
// Routing DS audit: ~30-34 DS ops/wave/round ~= measured 4.3us/round ->
// DS-throughput bound; pass2's uhat row RE-READ (4-6 b128) is the largest
// removable term. R26 fuses pass1+pass2 via per-lane online softmax:
//   per row: dp->L; if L>m_run { sa *= exp(m_run-L); m_run=L } (rare);
//   sa += exp(L-m_run)*row  -- row still in regs, read ONCE.
//   end: M=wave_max(m_run); sa *= exp(m_run-M); se=wave_sum(sel).
// Exact math (monotone rescale, ev<=1, f16-safe). Store (e^M, se*e^M).
// Saves ~20% routing DS + duplicated row loop. VGPR must stay 32.
// Tripwires: bench regress >1us => revert R25 (DS theory wrong or spill).
// absmax budget 0.0078 (expect <=0.0059).
//
// u: [256][1152][8] f32; weight: [1152][10][8][16] f32; out: [256][10][16] f32

#define IC 1152
#define OC 10
#define NB 256
#define TILE_DW (IC * 8)              // dwords per batch tile (f16-packed)

#define NW_DW (IC * OC * 64)          // 737280 dwords: W as f16 n-pairs
#define NU_DW (NB * IC * 4)           // 1179648 dwords: u as f16 n-pairs
#define WS_NEED ((size_t)(NW_DW + NU_DW) * 4)
#define NWT (NW_DW / 4)               // 184320 W-convert threads (4 dw each)
#define NUT (NU_DW / 2)               // 589824 u-convert threads (2 dw each)

typedef float v2f __attribute__((ext_vector_type(2)));
typedef _Float16 h2 __attribute__((ext_vector_type(2)));

#if defined(__has_builtin)
#if __has_builtin(__builtin_amdgcn_fdot2)
#define HAVE_FDOT2 1
#endif
#endif

__device__ __forceinline__ float fdot2f(unsigned w, unsigned uu, float c) {
    h2 a = *(h2*)&w, b = *(h2*)&uu;
#ifdef HAVE_FDOT2
    return __builtin_amdgcn_fdot2(a, b, c, false);
#else
    return c + (float)a.x * (float)b.x + (float)a.y * (float)b.y;
#endif
}
__device__ __forceinline__ v2f h_v2(unsigned w) {
    h2 h = *(h2*)&w;
    v2f r = {(float)h.x, (float)h.y};
    return r;
}
__device__ __forceinline__ unsigned packh2(float a, float b) {
    h2 h = {(_Float16)a, (_Float16)b};
    return *(unsigned*)&h;
}
__device__ __forceinline__ unsigned h2u(h2 v) { return *(unsigned*)&v; }
__device__ __forceinline__ h2 u2h(unsigned v) { return *(h2*)&v; }
__device__ __forceinline__ h2 hshfl_xor(h2 v, int m) {
    unsigned b = *(unsigned*)&v;
    unsigned r = (unsigned)__shfl_xor((int)b, m, 64);
    return *(h2*)&r;
}

// ---- DPP reduce primitives (VALU pipe) ----
__device__ __forceinline__ float dpp_wave_max(float x) {
    int v = __float_as_int(x);
    int t;
#define MSTEP(ctrl) \
    t = __builtin_amdgcn_update_dpp(0xFF800000, v, (ctrl), 0xF, 0xF, false); \
    v = __float_as_int(fmaxf(__int_as_float(v), __int_as_float(t)));
    MSTEP(0x111) MSTEP(0x112) MSTEP(0x114) MSTEP(0x118) MSTEP(0x142) MSTEP(0x143)
#undef MSTEP
    return __int_as_float(__builtin_amdgcn_readlane(v, 63));
}
__device__ __forceinline__ float dpp_wave_sum(float x) {
    int v = __float_as_int(x);
    int t;
#define SSTEP(ctrl) \
    t = __builtin_amdgcn_update_dpp(0, v, (ctrl), 0xF, 0xF, false); \
    v = __float_as_int(__int_as_float(v) + __int_as_float(t));
    SSTEP(0x111) SSTEP(0x112) SSTEP(0x114) SSTEP(0x118) SSTEP(0x142) SSTEP(0x143)
#undef SSTEP
    return __int_as_float(__builtin_amdgcn_readlane(v, 63));
}
template<int CTRL> __device__ __forceinline__ float qadd(float x) {
    int t = __builtin_amdgcn_update_dpp(0, __float_as_int(x), CTRL, 0xF, 0xF, false);
    return x + __int_as_float(t);
}
template<int CTRL> __device__ __forceinline__ h2 hqadd(h2 v) {
    int t = __builtin_amdgcn_update_dpp(0, (int)h2u(v), CTRL, 0xF, 0xF, false);
    return v + u2h((unsigned)t);
}

// ---- Pre-pass (vectorized, R23): W f32 -> f16 n-pairs; u f32 -> f16 pairs ----
__global__ void convert_kernel(const float* __restrict__ u,
                               const float* __restrict__ W,
                               unsigned* __restrict__ ws, int do_u) {
    const int tid = blockIdx.x * blockDim.x + threadIdx.x;
    if (tid < NWT) {
        const int k = tid & 3, q = (tid >> 2) & 3, ij = tid >> 4;
        const float* base = W + ((size_t)ij << 7) + (k << 5) + (q << 2);
        const float4 A = *(const float4*)base;        // W[ij][2k][q*4 .. +3]
        const float4 B = *(const float4*)(base + 16); // W[ij][2k+1][q*4 .. +3]
        unsigned* o = ws + ij * 64 + q * 16 + k;
        o[0]  = packh2(A.x, B.x);
        o[4]  = packh2(A.y, B.y);
        o[8]  = packh2(A.z, B.z);
        o[12] = packh2(A.w, B.w);
    } else if (do_u) {
        const int e = tid - NWT;
        if (e < NUT) {
            const float4 a = *(const float4*)(u + ((size_t)e << 2));
            *(uint2*)(ws + NW_DW + (e << 1)) =
                make_uint2(packh2(a.x, a.y), packh2(a.z, a.w));
        }
    }
}

template<bool UF16>
__global__ __launch_bounds__(1024, 8)
void caps_route_kernel(const float* __restrict__ u,
                       const unsigned* __restrict__ Wh,
                       const unsigned* __restrict__ ug,
                       float* __restrict__ out) {
    extern __shared__ unsigned smem_u[];
    unsigned* uh   = smem_u;                 // 2 tiles (73728 B)
    unsigned* r0p  = uh + 2 * TILE_DW;       // [2 bt][8 cp][20 pad] f16 (1280 B)
    unsigned* spart = r0p + 320;             // [2 par][[bt][cp*12][w8] 192 | eM,se*eM 32]

    const int t    = threadIdx.x;
    const int bx   = blockIdx.x;
    const int lane = t & 63;
    const int wid  = t >> 6;

    // p-major XCD mapping (xcd = bx & 7): XCD x gets p === x (mod 8)
    // -> per-XCD L2 footprint = full W (2.95MB) + u slice (0.59MB) < 4MB.
    const int x = bx & 7, g = bx >> 3;       // g in [0,160)
    const int j = g >> 4;                    // g/16: 0..9
    const int p = ((g & 15) << 3) + x;       // 0..127, p%8 == x
    const int bb = p * 2;                    // batches bb, bb+1

    // ---- Phase A: uhat -> LDS f16 (half-XOR swizzle) + r0 column sums ----
    {
        const int q  = t & 3;
        const int i0 = t >> 2;           // 0..255
        const int pb = (((q >> 1) ^ ((i0 >> 2) & 1)) << 2) + ((q & 1) << 1);
        const float* u0p = u + (size_t)bb * (IC * 8);
        const uint4* ua4 = (const uint4*)ug + (size_t)bb * IC;
        const uint4* ub4 = ua4 + IC;

        h2 sA01 = u2h(0u), sA23 = u2h(0u);
        h2 sB01 = u2h(0u), sB23 = u2h(0u);

        auto stage = [&](int i) {
            const uint4* wq4 = (const uint4*)Wh + (((size_t)(i * OC + j) << 2) + q) * 4;
            uint4 Ua, Ub;
            if constexpr (UF16) {
                Ua = ua4[i];
                Ub = ub4[i];
            } else {
                const float4 a0 = *(const float4*)(u0p + i * 8);
                const float4 a1 = *(const float4*)(u0p + i * 8 + 4);
                const float4 b0 = *(const float4*)(u0p + IC * 8 + i * 8);
                const float4 b1 = *(const float4*)(u0p + IC * 8 + i * 8 + 4);
                Ua = make_uint4(packh2(a0.x, a0.y), packh2(a0.z, a0.w),
                                packh2(a1.x, a1.y), packh2(a1.z, a1.w));
                Ub = make_uint4(packh2(b0.x, b0.y), packh2(b0.z, b0.w),
                                packh2(b1.x, b1.y), packh2(b1.z, b1.w));
            }
#define DOT8(acc, wm, Um) \
            acc = fdot2f(wm.x, Um.x, 0.f);  acc = fdot2f(wm.y, Um.y, acc); \
            acc = fdot2f(wm.z, Um.z, acc);  acc = fdot2f(wm.w, Um.w, acc);
            const uint4 w0 = wq4[0], w1 = wq4[1];
            float A0, A1, B0, B1;
            DOT8(A0, w0, Ua) DOT8(A1, w1, Ua)
            DOT8(B0, w0, Ub) DOT8(B1, w1, Ub)
            const unsigned pa01 = packh2(A0, A1), pb01 = packh2(B0, B1);
            const uint4 w2 = wq4[2], w3 = wq4[3];
            float A2, A3, B2, B3;
            DOT8(A2, w2, Ua) DOT8(A3, w3, Ua)
            DOT8(B2, w2, Ub) DOT8(B3, w3, Ub)
            const unsigned pa23 = packh2(A2, A3), pb23 = packh2(B2, B3);
#undef DOT8
            sA01 += u2h(pa01);  sA23 += u2h(pa23);
            sB01 += u2h(pb01);  sB23 += u2h(pb23);
            const int dst = (i << 3) + pb;
            *(uint2*)&uh[dst]           = make_uint2(pa01, pa23);
            *(uint2*)&uh[TILE_DW + dst] = make_uint2(pb01, pb23);
        };
#pragma unroll
        for (int k = 0; k < 4; ++k) stage(i0 + 256 * k);
        if (i0 < IC - 1024) stage(i0 + 1024);

#pragma unroll
        for (int o = 4; o <= 32; o <<= 1) {
            sA01 += hshfl_xor(sA01, o);  sA23 += hshfl_xor(sA23, o);
            sB01 += hshfl_xor(sB01, o);  sB23 += hshfl_xor(sB23, o);
        }
        if (lane < 4) {   // lane == q here; cp = 2q, 2q+1; padded stride 20
            const int c0 = lane << 1;
            r0p[c0 * 20 + wid]             = h2u(sA01);
            r0p[(c0 + 1) * 20 + wid]       = h2u(sA23);
            r0p[160 + c0 * 20 + wid]       = h2u(sB01);
            r0p[160 + (c0 + 1) * 20 + wid] = h2u(sB23);
        }
    }

    __syncthreads();  // B0: uhat + r0 partials ready

    // ---- Routing: balanced partition. Waves 0-5: 128 rows (2 passes);
    //      waves 6-7: 192 rows (3 passes). All passes full-wave. ----
    const int bt = wid >> 3;
    const int w8 = wid & 7;
    const bool w3p = (w8 >= 6);
    const int base0 = w3p ? (768 + (w8 - 6) * 192) : (w8 << 7);  // % 8 == 0
    const unsigned* uhT = uh + bt * TILE_DW;

    const int cp = lane & 7;               // m-pair this lane combines/stores
    const int i1 = base0 + lane, i2 = i1 + 64, i3 = base0 + 128 + lane;

    float L0 = 0.f, L1 = 0.f, L2 = 0.f;

    for (int r = 0; r < 3; ++r) {
        if (r == 2 && w8 != 0) break;      // only w8==0 produces output

        // ---- combine -> s -> squash -> v (per-lane m-pair cp) ----
        float sx, sy;
        {
            v2f s2 = {0.f, 0.f};
            float inv;
            if (r == 0) {
                // r0p[bt][cp][16 of 20]: 4 x b128, two halves (VGPR guard)
                const unsigned* rp = &r0p[bt * 160 + cp * 20];
                h2 a2 = u2h(0u);
                {
                    const uint4 v0 = *(const uint4*)&rp[0];
                    const uint4 v1 = *(const uint4*)&rp[4];
                    a2 += u2h(v0.x) + u2h(v0.y) + u2h(v0.z) + u2h(v0.w);
                    a2 += u2h(v1.x) + u2h(v1.y) + u2h(v1.z) + u2h(v1.w);
                }
                {
                    const uint4 v2 = *(const uint4*)&rp[8];
                    const uint4 v3 = *(const uint4*)&rp[12];
                    a2 += u2h(v2.x) + u2h(v2.y) + u2h(v2.z) + u2h(v2.w);
                    a2 += u2h(v3.x) + u2h(v3.y) + u2h(v3.z) + u2h(v3.w);
                }
                s2.x = (float)a2.x; s2.y = (float)a2.y;
                inv = 1.0f / (float)IC;
            } else {
                const int base = ((r - 1) & 1) * 224;
                const unsigned* pp = &spart[base + bt * 96 + cp * 12];
                const unsigned* ee = &spart[base + 192 + bt * 16];
                float ses = 0.f;
#define CW(pw, fm, fs) { \
                const float fac = __uint_as_float(fm); \
                const v2f pv = h_v2(pw); \
                s2.x += pv.x * fac;  s2.y += pv.y * fac; \
                ses += __uint_as_float(fs); }
                {   // half 1: w = 0..3
                    const uint4 P0 = *(const uint4*)&pp[0];
                    const uint4 E0 = *(const uint4*)&ee[0];
                    const uint4 E1 = *(const uint4*)&ee[4];
                    CW(P0.x, E0.x, E0.y) CW(P0.y, E0.z, E0.w)
                    CW(P0.z, E1.x, E1.y) CW(P0.w, E1.z, E1.w)
                }
                {   // half 2: w = 4..7
                    const uint4 P1 = *(const uint4*)&pp[4];
                    const uint4 E2 = *(const uint4*)&ee[8];
                    const uint4 E3 = *(const uint4*)&ee[12];
                    CW(P1.x, E2.x, E2.y) CW(P1.y, E2.z, E2.w)
                    CW(P1.z, E3.x, E3.y) CW(P1.w, E3.z, E3.w)
                }
#undef CW
                inv = 1.0f / ses;
            }
            sx = s2.x * inv;  sy = s2.y * inv;
        }
        float p2 = sx * sx + sy * sy;
        p2 = qadd<0xB1>(p2);               // xor1 (quad_perm, VALU)
        p2 = qadd<0x4E>(p2);               // xor2
        p2 += __int_as_float(__builtin_amdgcn_ds_swizzle(__float_as_int(p2), 0x101F)); // xor4
        const float sc = p2 / ((1.0f + p2) * sqrtf(p2 + 1e-8f));
        const float vx = sx * sc, vy = sy * sc;

        if (r == 2) {
            if (lane < 8)
                *(float2*)&out[((size_t)(bb + bt) * OC + j) * 16 + (cp << 1)] =
                    make_float2(vx, vy);
            break;
        }

        // ---- broadcast v into position space: compile-time ds_swizzle ----
        const int pki = (int)packh2(vx, vy);
        unsigned vh[8];
        vh[0] = (unsigned)__builtin_amdgcn_ds_swizzle(pki, 0x001C);
        vh[1] = (unsigned)__builtin_amdgcn_ds_swizzle(pki, 0x003C);
        vh[2] = (unsigned)__builtin_amdgcn_ds_swizzle(pki, 0x005C);
        vh[3] = (unsigned)__builtin_amdgcn_ds_swizzle(pki, 0x007C);
        vh[4] = (unsigned)__builtin_amdgcn_ds_swizzle(pki, 0x101C);
        vh[5] = (unsigned)__builtin_amdgcn_ds_swizzle(pki, 0x103C);
        vh[6] = (unsigned)__builtin_amdgcn_ds_swizzle(pki, 0x105C);
        vh[7] = (unsigned)__builtin_amdgcn_ds_swizzle(pki, 0x107C);

        // ---- single-pass online b-update: rows read ONCE ----
        h2 sa[8];
#pragma unroll
        for (int k = 0; k < 8; ++k) sa[k] = u2h(0u);
        float sel = 0.f;
        float mrun = -1e30f;
#define BROW(Lk, ii) { \
        const uint4 da = *(const uint4*)&uhT[(ii) << 3]; \
        const uint4 db = *(const uint4*)&uhT[((ii) << 3) + 4]; \
        float d1 = fdot2f(da.x, vh[0], 0.f); d1 = fdot2f(da.y, vh[1], d1); \
        d1 = fdot2f(da.z, vh[2], d1); d1 = fdot2f(da.w, vh[3], d1); \
        float d2 = fdot2f(db.x, vh[4], 0.f); d2 = fdot2f(db.y, vh[5], d2); \
        d2 = fdot2f(db.z, vh[6], d2); d2 = fdot2f(db.w, vh[7], d2); \
        (Lk) += d1 + d2; \
        if ((Lk) > mrun) { \
            const float rs = __expf(mrun - (Lk)); \
            const h2 rh = u2h(packh2(rs, rs)); \
            sa[0] *= rh; sa[1] *= rh; sa[2] *= rh; sa[3] *= rh; \
            sa[4] *= rh; sa[5] *= rh; sa[6] *= rh; sa[7] *= rh; \
            sel *= rs; mrun = (Lk); \
        } \
        const float ev = __expf((Lk) - mrun); \
        sel += ev; \
        const h2 eh = u2h(packh2(ev, ev)); \
        sa[0] += u2h(da.x) * eh;  sa[1] += u2h(da.y) * eh; \
        sa[2] += u2h(da.z) * eh;  sa[3] += u2h(da.w) * eh; \
        sa[4] += u2h(db.x) * eh;  sa[5] += u2h(db.y) * eh; \
        sa[6] += u2h(db.z) * eh;  sa[7] += u2h(db.w) * eh; }
        BROW(L0, i1)
        BROW(L1, i2)
        if (w3p) { BROW(L2, i3) }
#undef BROW

        // ---- uniform-ize to wave max; reduce se ----
        const float M = dpp_wave_max(mrun);
        {
            const float fx = __expf(mrun - M);
            const h2 fh = u2h(packh2(fx, fx));
#pragma unroll
            for (int k = 0; k < 8; ++k) sa[k] *= fh;
            sel *= fx;
        }
        const float se = dpp_wave_sum(sel);

        // ---- narrowing XOR tree; step1 selects on (lane5 ^ eB) => m-space ----
        h2 tt;
        {
            const int eB = (lane >> 2) & 1;
            const bool s5 = (((lane >> 5) & 1) ^ eB) != 0;
            const bool b4 = (lane & 16) != 0, b3 = (lane & 8) != 0;
            h2 tq[4];
#pragma unroll
            for (int q = 0; q < 4; ++q) {
                h2 snd = s5 ? sa[q] : sa[q + 4];
                tq[q] = (s5 ? sa[q + 4] : sa[q]) + hshfl_xor(snd, 32);
            }
            h2 uq[2];
#pragma unroll
            for (int q = 0; q < 2; ++q) {
                h2 snd = b4 ? tq[q] : tq[q + 2];
                uq[q] = (b4 ? tq[q + 2] : tq[q]) + hshfl_xor(snd, 16);
            }
            {
                h2 snd = b3 ? uq[0] : uq[1];
                tt = (b3 ? uq[1] : uq[0]) + hshfl_xor(snd, 8);
            }
            tt += u2h((unsigned)__builtin_amdgcn_ds_swizzle((int)h2u(tt), 0x101F)); // xor4
            tt = hqadd<0x4E>(tt);          // xor2 (quad_perm)
            tt = hqadd<0xB1>(tt);          // xor1
        }

        // ---- store partials: [bt][cp*12][w8] (padded) + (e^M, se*e^M) ----
        const int po = (r & 1) * 224;
        if ((lane & 7) == 0)
            spart[po + bt * 96 + (lane >> 3) * 12 + w8] = h2u(tt);
        if (lane == 1) {
            const float em = __expf(M);
            *(float2*)&spart[po + 192 + (bt * 8 + w8) * 2] = make_float2(em, se * em);
        }
        __syncthreads();  // B(r+1)
    }
}

extern "C" void kernel_launch(void* const* d_in, const int* in_sizes, int n_in,
                              void* d_out, int out_size, void* d_ws, size_t ws_size,
                              hipStream_t stream) {
    const float* u = (const float*)d_in[0];
    const float* W = (const float*)d_in[1];
    float* out = (float*)d_out;
    unsigned* ws = (unsigned*)d_ws;

    const int do_u = (ws_size >= WS_NEED) ? 1 : 0;
    const int total = NWT + (do_u ? NUT : 0);
    convert_kernel<<<(total + 255) / 256, 256, 0, stream>>>(u, W, ws, do_u);

    const size_t shmem = (size_t)(2 * TILE_DW + 320 + 448) * 4;  // 76800 B
    if (do_u) {
        hipFuncSetAttribute((const void*)caps_route_kernel<true>,
                            hipFuncAttributeMaxDynamicSharedMemorySize, (int)shmem);
        caps_route_kernel<true><<<(NB / 2) * OC, 1024, shmem, stream>>>(u, ws, ws + NW_DW, out);
    } else {
        hipFuncSetAttribute((const void*)caps_route_kernel<false>,
                            hipFuncAttributeMaxDynamicSharedMemorySize, (int)shmem);
        caps_route_kernel<false><<<(NB / 2) * OC, 1024, shmem, stream>>>(u, ws, ws + NW_DW, out);
    }
}

// Round 11
// 101.971 us; speedup vs baseline: 1.0198x; 1.0198x over previous
//
#include <hip/hip_runtime.h>
#include <hip/hip_bf16.h>
#include <math.h>

// CapsNet dynamic routing. R27 = exact R25 revert (best verified config).
// R26 post-mortem: single-pass online softmax REGRESSED (42.5 -> 45.0us):
// per-row mrun/sa dependency chain serialized the row loop; two-pass has
// fully independent rows per pass (ILP > DS savings). Same family as R22:
// kernel is latency/ILP-bound; op-count cuts that lengthen dependency
// chains lose. R25 config: p-major XCD mapping (FETCH 13.9MB), padded
// partial strides (conflicts 0.65-0.74M), balanced rows (18 full-wave
// passes), two-pass b-update, DPP reduces, 3 barriers.
// Tripwires: VGPR == 32, WRITE_SIZE ~160KB, absmax == 0.00390625.
//
// u: [256][1152][8] f32; weight: [1152][10][8][16] f32; out: [256][10][16] f32

#define IC 1152
#define OC 10
#define NB 256
#define TILE_DW (IC * 8)              // dwords per batch tile (f16-packed)

#define NW_DW (IC * OC * 64)          // 737280 dwords: W as f16 n-pairs
#define NU_DW (NB * IC * 4)           // 1179648 dwords: u as f16 n-pairs
#define WS_NEED ((size_t)(NW_DW + NU_DW) * 4)
#define NWT (NW_DW / 4)               // 184320 W-convert threads (4 dw each)
#define NUT (NU_DW / 2)               // 589824 u-convert threads (2 dw each)

typedef float v2f __attribute__((ext_vector_type(2)));
typedef _Float16 h2 __attribute__((ext_vector_type(2)));

#if defined(__has_builtin)
#if __has_builtin(__builtin_amdgcn_fdot2)
#define HAVE_FDOT2 1
#endif
#endif

__device__ __forceinline__ float fdot2f(unsigned w, unsigned uu, float c) {
    h2 a = *(h2*)&w, b = *(h2*)&uu;
#ifdef HAVE_FDOT2
    return __builtin_amdgcn_fdot2(a, b, c, false);
#else
    return c + (float)a.x * (float)b.x + (float)a.y * (float)b.y;
#endif
}
__device__ __forceinline__ v2f h_v2(unsigned w) {
    h2 h = *(h2*)&w;
    v2f r = {(float)h.x, (float)h.y};
    return r;
}
__device__ __forceinline__ unsigned packh2(float a, float b) {
    h2 h = {(_Float16)a, (_Float16)b};
    return *(unsigned*)&h;
}
__device__ __forceinline__ unsigned h2u(h2 v) { return *(unsigned*)&v; }
__device__ __forceinline__ h2 u2h(unsigned v) { return *(h2*)&v; }
__device__ __forceinline__ h2 hshfl_xor(h2 v, int m) {
    unsigned b = *(unsigned*)&v;
    unsigned r = (unsigned)__shfl_xor((int)b, m, 64);
    return *(h2*)&r;
}

// ---- DPP reduce primitives (VALU pipe) ----
__device__ __forceinline__ float dpp_wave_max(float x) {
    int v = __float_as_int(x);
    int t;
#define MSTEP(ctrl) \
    t = __builtin_amdgcn_update_dpp(0xFF800000, v, (ctrl), 0xF, 0xF, false); \
    v = __float_as_int(fmaxf(__int_as_float(v), __int_as_float(t)));
    MSTEP(0x111) MSTEP(0x112) MSTEP(0x114) MSTEP(0x118) MSTEP(0x142) MSTEP(0x143)
#undef MSTEP
    return __int_as_float(__builtin_amdgcn_readlane(v, 63));
}
__device__ __forceinline__ float dpp_wave_sum(float x) {
    int v = __float_as_int(x);
    int t;
#define SSTEP(ctrl) \
    t = __builtin_amdgcn_update_dpp(0, v, (ctrl), 0xF, 0xF, false); \
    v = __float_as_int(__int_as_float(v) + __int_as_float(t));
    SSTEP(0x111) SSTEP(0x112) SSTEP(0x114) SSTEP(0x118) SSTEP(0x142) SSTEP(0x143)
#undef SSTEP
    return __int_as_float(__builtin_amdgcn_readlane(v, 63));
}
template<int CTRL> __device__ __forceinline__ float qadd(float x) {
    int t = __builtin_amdgcn_update_dpp(0, __float_as_int(x), CTRL, 0xF, 0xF, false);
    return x + __int_as_float(t);
}
template<int CTRL> __device__ __forceinline__ h2 hqadd(h2 v) {
    int t = __builtin_amdgcn_update_dpp(0, (int)h2u(v), CTRL, 0xF, 0xF, false);
    return v + u2h((unsigned)t);
}

// ---- Pre-pass (vectorized, R23): W f32 -> f16 n-pairs; u f32 -> f16 pairs ----
__global__ void convert_kernel(const float* __restrict__ u,
                               const float* __restrict__ W,
                               unsigned* __restrict__ ws, int do_u) {
    const int tid = blockIdx.x * blockDim.x + threadIdx.x;
    if (tid < NWT) {
        const int k = tid & 3, q = (tid >> 2) & 3, ij = tid >> 4;
        const float* base = W + ((size_t)ij << 7) + (k << 5) + (q << 2);
        const float4 A = *(const float4*)base;        // W[ij][2k][q*4 .. +3]
        const float4 B = *(const float4*)(base + 16); // W[ij][2k+1][q*4 .. +3]
        unsigned* o = ws + ij * 64 + q * 16 + k;
        o[0]  = packh2(A.x, B.x);
        o[4]  = packh2(A.y, B.y);
        o[8]  = packh2(A.z, B.z);
        o[12] = packh2(A.w, B.w);
    } else if (do_u) {
        const int e = tid - NWT;
        if (e < NUT) {
            const float4 a = *(const float4*)(u + ((size_t)e << 2));
            *(uint2*)(ws + NW_DW + (e << 1)) =
                make_uint2(packh2(a.x, a.y), packh2(a.z, a.w));
        }
    }
}

template<bool UF16>
__global__ __launch_bounds__(1024, 8)
void caps_route_kernel(const float* __restrict__ u,
                       const unsigned* __restrict__ Wh,
                       const unsigned* __restrict__ ug,
                       float* __restrict__ out) {
    extern __shared__ unsigned smem_u[];
    unsigned* uh   = smem_u;                 // 2 tiles (73728 B)
    unsigned* r0p  = uh + 2 * TILE_DW;       // [2 bt][8 cp][20 pad] f16 (1280 B)
    unsigned* spart = r0p + 320;             // [2 par][[bt][cp*12][w8] 192 | expM,se 32]

    const int t    = threadIdx.x;
    const int bx   = blockIdx.x;
    const int lane = t & 63;
    const int wid  = t >> 6;

    // p-major XCD mapping (xcd = bx & 7): XCD x gets p === x (mod 8)
    // -> per-XCD L2 footprint = full W (2.95MB) + u slice (0.59MB) < 4MB.
    const int x = bx & 7, g = bx >> 3;       // g in [0,160)
    const int j = g >> 4;                    // g/16: 0..9
    const int p = ((g & 15) << 3) + x;       // 0..127, p%8 == x
    const int bb = p * 2;                    // batches bb, bb+1

    // ---- Phase A: uhat -> LDS f16 (half-XOR swizzle) + r0 column sums ----
    {
        const int q  = t & 3;
        const int i0 = t >> 2;           // 0..255
        const int pb = (((q >> 1) ^ ((i0 >> 2) & 1)) << 2) + ((q & 1) << 1);
        const float* u0p = u + (size_t)bb * (IC * 8);
        const uint4* ua4 = (const uint4*)ug + (size_t)bb * IC;
        const uint4* ub4 = ua4 + IC;

        h2 sA01 = u2h(0u), sA23 = u2h(0u);
        h2 sB01 = u2h(0u), sB23 = u2h(0u);

        auto stage = [&](int i) {
            const uint4* wq4 = (const uint4*)Wh + (((size_t)(i * OC + j) << 2) + q) * 4;
            uint4 Ua, Ub;
            if constexpr (UF16) {
                Ua = ua4[i];
                Ub = ub4[i];
            } else {
                const float4 a0 = *(const float4*)(u0p + i * 8);
                const float4 a1 = *(const float4*)(u0p + i * 8 + 4);
                const float4 b0 = *(const float4*)(u0p + IC * 8 + i * 8);
                const float4 b1 = *(const float4*)(u0p + IC * 8 + i * 8 + 4);
                Ua = make_uint4(packh2(a0.x, a0.y), packh2(a0.z, a0.w),
                                packh2(a1.x, a1.y), packh2(a1.z, a1.w));
                Ub = make_uint4(packh2(b0.x, b0.y), packh2(b0.z, b0.w),
                                packh2(b1.x, b1.y), packh2(b1.z, b1.w));
            }
#define DOT8(acc, wm, Um) \
            acc = fdot2f(wm.x, Um.x, 0.f);  acc = fdot2f(wm.y, Um.y, acc); \
            acc = fdot2f(wm.z, Um.z, acc);  acc = fdot2f(wm.w, Um.w, acc);
            const uint4 w0 = wq4[0], w1 = wq4[1];
            float A0, A1, B0, B1;
            DOT8(A0, w0, Ua) DOT8(A1, w1, Ua)
            DOT8(B0, w0, Ub) DOT8(B1, w1, Ub)
            const unsigned pa01 = packh2(A0, A1), pb01 = packh2(B0, B1);
            const uint4 w2 = wq4[2], w3 = wq4[3];
            float A2, A3, B2, B3;
            DOT8(A2, w2, Ua) DOT8(A3, w3, Ua)
            DOT8(B2, w2, Ub) DOT8(B3, w3, Ub)
            const unsigned pa23 = packh2(A2, A3), pb23 = packh2(B2, B3);
#undef DOT8
            sA01 += u2h(pa01);  sA23 += u2h(pa23);
            sB01 += u2h(pb01);  sB23 += u2h(pb23);
            const int dst = (i << 3) + pb;
            *(uint2*)&uh[dst]           = make_uint2(pa01, pa23);
            *(uint2*)&uh[TILE_DW + dst] = make_uint2(pb01, pb23);
        };
#pragma unroll
        for (int k = 0; k < 4; ++k) stage(i0 + 256 * k);
        if (i0 < IC - 1024) stage(i0 + 1024);

#pragma unroll
        for (int o = 4; o <= 32; o <<= 1) {
            sA01 += hshfl_xor(sA01, o);  sA23 += hshfl_xor(sA23, o);
            sB01 += hshfl_xor(sB01, o);  sB23 += hshfl_xor(sB23, o);
        }
        if (lane < 4) {   // lane == q here; cp = 2q, 2q+1; padded stride 20
            const int c0 = lane << 1;
            r0p[c0 * 20 + wid]             = h2u(sA01);
            r0p[(c0 + 1) * 20 + wid]       = h2u(sA23);
            r0p[160 + c0 * 20 + wid]       = h2u(sB01);
            r0p[160 + (c0 + 1) * 20 + wid] = h2u(sB23);
        }
    }

    __syncthreads();  // B0: uhat + r0 partials ready

    // ---- Routing: balanced partition. Waves 0-5: 128 rows (2 passes);
    //      waves 6-7: 192 rows (3 passes). All passes full-wave. ----
    const int bt = wid >> 3;
    const int w8 = wid & 7;
    const bool w3p = (w8 >= 6);
    const int base0 = w3p ? (768 + (w8 - 6) * 192) : (w8 << 7);  // % 8 == 0
    const unsigned* uhT = uh + bt * TILE_DW;

    const int cp = lane & 7;               // m-pair this lane combines/stores
    const int i1 = base0 + lane, i2 = i1 + 64, i3 = base0 + 128 + lane;

    float L0 = 0.f, L1 = 0.f, L2 = w3p ? 0.f : -1e30f;

    for (int r = 0; r < 3; ++r) {
        if (r == 2 && w8 != 0) break;      // only w8==0 produces output

        // ---- combine -> s -> squash -> v (per-lane m-pair cp) ----
        float sx, sy;
        {
            v2f s2 = {0.f, 0.f};
            float inv;
            if (r == 0) {
                // r0p[bt][cp][16 of 20]: 4 x b128, two halves (VGPR guard)
                const unsigned* rp = &r0p[bt * 160 + cp * 20];
                h2 a2 = u2h(0u);
                {
                    const uint4 v0 = *(const uint4*)&rp[0];
                    const uint4 v1 = *(const uint4*)&rp[4];
                    a2 += u2h(v0.x) + u2h(v0.y) + u2h(v0.z) + u2h(v0.w);
                    a2 += u2h(v1.x) + u2h(v1.y) + u2h(v1.z) + u2h(v1.w);
                }
                {
                    const uint4 v2 = *(const uint4*)&rp[8];
                    const uint4 v3 = *(const uint4*)&rp[12];
                    a2 += u2h(v2.x) + u2h(v2.y) + u2h(v2.z) + u2h(v2.w);
                    a2 += u2h(v3.x) + u2h(v3.y) + u2h(v3.z) + u2h(v3.w);
                }
                s2.x = (float)a2.x; s2.y = (float)a2.y;
                inv = 1.0f / (float)IC;
            } else {
                const int base = ((r - 1) & 1) * 224;
                const unsigned* pp = &spart[base + bt * 96 + cp * 12];
                const unsigned* ee = &spart[base + 192 + bt * 16];
                float ses = 0.f;
#define CW(pw, fm, fs) { \
                const float fac = __uint_as_float(fm); \
                const v2f pv = h_v2(pw); \
                s2.x += pv.x * fac;  s2.y += pv.y * fac; \
                ses += __uint_as_float(fs) * fac; }
                {   // half 1: w = 0..3
                    const uint4 P0 = *(const uint4*)&pp[0];
                    const uint4 E0 = *(const uint4*)&ee[0];
                    const uint4 E1 = *(const uint4*)&ee[4];
                    CW(P0.x, E0.x, E0.y) CW(P0.y, E0.z, E0.w)
                    CW(P0.z, E1.x, E1.y) CW(P0.w, E1.z, E1.w)
                }
                {   // half 2: w = 4..7
                    const uint4 P1 = *(const uint4*)&pp[4];
                    const uint4 E2 = *(const uint4*)&ee[8];
                    const uint4 E3 = *(const uint4*)&ee[12];
                    CW(P1.x, E2.x, E2.y) CW(P1.y, E2.z, E2.w)
                    CW(P1.z, E3.x, E3.y) CW(P1.w, E3.z, E3.w)
                }
#undef CW
                inv = 1.0f / ses;
            }
            sx = s2.x * inv;  sy = s2.y * inv;
        }
        float p2 = sx * sx + sy * sy;
        p2 = qadd<0xB1>(p2);               // xor1 (quad_perm, VALU)
        p2 = qadd<0x4E>(p2);               // xor2
        p2 += __int_as_float(__builtin_amdgcn_ds_swizzle(__float_as_int(p2), 0x101F)); // xor4
        const float sc = p2 / ((1.0f + p2) * sqrtf(p2 + 1e-8f));
        const float vx = sx * sc, vy = sy * sc;

        if (r == 2) {
            if (lane < 8)
                *(float2*)&out[((size_t)(bb + bt) * OC + j) * 16 + (cp << 1)] =
                    make_float2(vx, vy);
            break;
        }

        // ---- broadcast v into position space: compile-time ds_swizzle ----
        const int pki = (int)packh2(vx, vy);
        unsigned vh[8];
        vh[0] = (unsigned)__builtin_amdgcn_ds_swizzle(pki, 0x001C);
        vh[1] = (unsigned)__builtin_amdgcn_ds_swizzle(pki, 0x003C);
        vh[2] = (unsigned)__builtin_amdgcn_ds_swizzle(pki, 0x005C);
        vh[3] = (unsigned)__builtin_amdgcn_ds_swizzle(pki, 0x007C);
        vh[4] = (unsigned)__builtin_amdgcn_ds_swizzle(pki, 0x101C);
        vh[5] = (unsigned)__builtin_amdgcn_ds_swizzle(pki, 0x103C);
        vh[6] = (unsigned)__builtin_amdgcn_ds_swizzle(pki, 0x105C);
        vh[7] = (unsigned)__builtin_amdgcn_ds_swizzle(pki, 0x107C);

        // ---- pass1: dp -> L (all passes full-wave) ----
#define DP8(Lk, ii) { \
        const uint4 da = *(const uint4*)&uhT[(ii) << 3]; \
        const uint4 db = *(const uint4*)&uhT[((ii) << 3) + 4]; \
        float d1 = fdot2f(da.x, vh[0], 0.f); d1 = fdot2f(da.y, vh[1], d1); \
        d1 = fdot2f(da.z, vh[2], d1); d1 = fdot2f(da.w, vh[3], d1); \
        float d2 = fdot2f(db.x, vh[4], 0.f); d2 = fdot2f(db.y, vh[5], d2); \
        d2 = fdot2f(db.z, vh[6], d2); d2 = fdot2f(db.w, vh[7], d2); \
        (Lk) += d1 + d2; }
        DP8(L0, i1)
        DP8(L1, i2)
        if (w3p) { DP8(L2, i3) }
#undef DP8

        // ---- wave max via DPP ladder (range guard for f16 partials) ----
        const float M = dpp_wave_max(fmaxf(L0, fmaxf(L1, L2)));

        // ---- pass2: ev = exp(L-M); se; s-partials via v_pk_fma_f16 ----
        h2 sa[8];
#pragma unroll
        for (int k = 0; k < 8; ++k) sa[k] = u2h(0u);
        float sel = 0.f;
#define ROW2(Lk, ii) { \
        const uint4 da = *(const uint4*)&uhT[(ii) << 3]; \
        const uint4 db = *(const uint4*)&uhT[((ii) << 3) + 4]; \
        const float ev = __expf((Lk) - M); \
        sel += ev; \
        const h2 eh = u2h(packh2(ev, ev)); \
        sa[0] += u2h(da.x) * eh;  sa[1] += u2h(da.y) * eh; \
        sa[2] += u2h(da.z) * eh;  sa[3] += u2h(da.w) * eh; \
        sa[4] += u2h(db.x) * eh;  sa[5] += u2h(db.y) * eh; \
        sa[6] += u2h(db.z) * eh;  sa[7] += u2h(db.w) * eh; }
        ROW2(L0, i1)
        ROW2(L1, i2)
        if (w3p) { ROW2(L2, i3) }
#undef ROW2
        const float se = dpp_wave_sum(sel);

        // ---- narrowing XOR tree; step1 selects on (lane5 ^ eB) => m-space ----
        h2 tt;
        {
            const int eB = (lane >> 2) & 1;
            const bool s5 = (((lane >> 5) & 1) ^ eB) != 0;
            const bool b4 = (lane & 16) != 0, b3 = (lane & 8) != 0;
            h2 tq[4];
#pragma unroll
            for (int q = 0; q < 4; ++q) {
                h2 snd = s5 ? sa[q] : sa[q + 4];
                tq[q] = (s5 ? sa[q + 4] : sa[q]) + hshfl_xor(snd, 32);
            }
            h2 uq[2];
#pragma unroll
            for (int q = 0; q < 2; ++q) {
                h2 snd = b4 ? tq[q] : tq[q + 2];
                uq[q] = (b4 ? tq[q + 2] : tq[q]) + hshfl_xor(snd, 16);
            }
            {
                h2 snd = b3 ? uq[0] : uq[1];
                tt = (b3 ? uq[1] : uq[0]) + hshfl_xor(snd, 8);
            }
            tt += u2h((unsigned)__builtin_amdgcn_ds_swizzle((int)h2u(tt), 0x101F)); // xor4
            tt = hqadd<0x4E>(tt);          // xor2 (quad_perm)
            tt = hqadd<0xB1>(tt);          // xor1
        }

        // ---- store partials: [bt][cp*12][w8] (padded) + (e^M, se)[bt][w8] ----
        const int po = (r & 1) * 224;
        if ((lane & 7) == 0)
            spart[po + bt * 96 + (lane >> 3) * 12 + w8] = h2u(tt);
        if (lane == 1)
            *(float2*)&spart[po + 192 + (bt * 8 + w8) * 2] = make_float2(__expf(M), se);
        __syncthreads();  // B(r+1)
    }
}

extern "C" void kernel_launch(void* const* d_in, const int* in_sizes, int n_in,
                              void* d_out, int out_size, void* d_ws, size_t ws_size,
                              hipStream_t stream) {
    const float* u = (const float*)d_in[0];
    const float* W = (const float*)d_in[1];
    float* out = (float*)d_out;
    unsigned* ws = (unsigned*)d_ws;

    const int do_u = (ws_size >= WS_NEED) ? 1 : 0;
    const int total = NWT + (do_u ? NUT : 0);
    convert_kernel<<<(total + 255) / 256, 256, 0, stream>>>(u, W, ws, do_u);

    const size_t shmem = (size_t)(2 * TILE_DW + 320 + 448) * 4;  // 76800 B
    if (do_u) {
        hipFuncSetAttribute((const void*)caps_route_kernel<true>,
                            hipFuncAttributeMaxDynamicSharedMemorySize, (int)shmem);
        caps_route_kernel<true><<<(NB / 2) * OC, 1024, shmem, stream>>>(u, ws, ws + NW_DW, out);
    } else {
        hipFuncSetAttribute((const void*)caps_route_kernel<false>,
                            hipFuncAttributeMaxDynamicSharedMemorySize, (int)shmem);
        caps_route_kernel<false><<<(NB / 2) * OC, 1024, shmem, stream>>>(u, ws, ws + NW_DW, out);
    }
}